// Round 13
// baseline (60.759 us; speedup 1.0000x reference)
//
#include <hip/hip_runtime.h>

// GNN layer: deg-normalized aggregation -> Linear+ReLU -> LayerNorm
// N=10000, E=640000, D=128. 4 dispatches (R12 structure + packed-W matmul):
//  D1 hist_pack:  128-block LDS packed histogram + per-edge ranks;
//                 side-work: WbT4 = bf16-packed W in uint4 quads.
//  D2 colscan:    8 lanes/bin shfl-combined block-prefix scan -> u16 pre16,
//                 in-deg cnt (capped PAD), dinv = 1/(outdeg+1).
//  D3 fillscale:  (A) HsU = bf16x2(H * dinv) pre-scale (contiguous);
//                 (B) padded-CSR fill of u16 src indices (stateless).
//  D4 aggmmln:    one node per wave (10000 waves): gather-add prescaled bf16
//                 rows (fp32 acc, 8-edge unroll), stage row in per-wave LDS,
//                 matmul via 32x dwordx4 WbT4 loads + ds_read_b128 broadcast
//                 (4x fewer mem insts than scalar) + bias + ReLU + LN.
// PAD=128: shift addressing, 256B edge rows (max in-deg ~110, ~8 sigma).

#define DFEAT 128
#define MAXN 10240
#define NBLK 128     // histogram partitions
#define PAD 128      // CSR slots/node (mean in-deg 64, max ~110; guarded)
#define SPLIT 8
#define KPT (NBLK / SPLIT)  // 16 hist-blocks per colscan lane

__device__ __forceinline__ unsigned bf16rne(float f) {
    unsigned u = __float_as_uint(f);
    return (u + 0x7fffu + ((u >> 16) & 1u)) >> 16;
}
__device__ __forceinline__ float bflo(unsigned u) { return __uint_as_float(u << 16); }
__device__ __forceinline__ float bfhi(unsigned u) { return __uint_as_float(u & 0xffff0000u); }

// D1: packed per-block histogram (low16=source/out-deg, high16=dest/in-deg;
// Epb=5000 so halves never carry), per-edge dest ranks; WbT4 pack side-work.
// WbT4[kk*64+l] = (A0,B0,A1,B1): A0=bf16x2(W[l][4kk],W[l][4kk+1]),
// B0=same rows for col l+64, A1/B1 = feats 4kk+2..3. kk=0..31, l=0..63.
__global__ __launch_bounds__(1024) void hist_pack_kernel(
    const int* __restrict__ ei, int E, int Epb, int N,
    const float* __restrict__ W, int* __restrict__ packedHist,
    unsigned short* __restrict__ rank16, uint4* __restrict__ WbT4) {
    __shared__ unsigned h[MAXN];
    int t = threadIdx.x, b = blockIdx.x;
    for (int i = t; i < N; i += 1024) h[i] = 0u;
    __syncthreads();
    {
        int e0 = b * Epb, e1 = min(E, e0 + Epb);
        for (int e = e0 + t; e < e1; e += 1024) {
            atomicAdd(&h[ei[e]], 1u);                               // source
            unsigned old = atomicAdd(&h[ei[E + e]], 0x10000u);      // dest
            rank16[e] = (unsigned short)(old >> 16);
        }
    }
    __syncthreads();
    for (int i = t; i < N; i += 1024) packedHist[b * N + i] = (int)h[i];
    // side-work: WbT4 pack (2048 entries; blocks 0-1 cover it)
    {
        int gid = b * 1024 + t;
        if (gid < 32 * 64) {
            int kk = gid >> 6, l = gid & 63;
            const float4 wa = *(const float4*)(W + l * 128 + 4 * kk);
            const float4 wb = *(const float4*)(W + (l + 64) * 128 + 4 * kk);
            uint4 o;
            o.x = bf16rne(wa.x) | (bf16rne(wa.y) << 16);  // A0
            o.y = bf16rne(wb.x) | (bf16rne(wb.y) << 16);  // B0
            o.z = bf16rne(wa.z) | (bf16rne(wa.w) << 16);  // A1
            o.w = bf16rne(wb.z) | (bf16rne(wb.w) << 16);  // B1
            WbT4[gid] = o;
        }
    }
}

// D2: per-bin, 8 lanes each scan 16 hist-blocks; shfl-combine across the
// 8-lane group; exclusive prefixes -> u16 pre16; in-deg cnt (capped); dinv.
__global__ __launch_bounds__(256) void colscan_kernel(
    const int* __restrict__ packedHist, unsigned short* __restrict__ pre16,
    float* __restrict__ dinv, int* __restrict__ cnt, int N) {
    int tid = blockIdx.x * 256 + threadIdx.x;
    int b = tid >> 3, p = tid & 7;
    if (b >= N) return;  // whole 8-lane groups drop together
    int lane = threadIdx.x & 63;
    int base = p * KPT;
    int sR = 0, sC = 0;
#pragma unroll
    for (int j = 0; j < KPT; ++j) {
        unsigned v = (unsigned)packedHist[(base + j) * N + b];
        sR += (int)(v & 0xffffu);
        sC += (int)(v >> 16);
    }
    int incl = sC;
    int u1 = __shfl_up(incl, 1); if (p >= 1) incl += u1;
    int u2 = __shfl_up(incl, 2); if (p >= 2) incl += u2;
    int u4 = __shfl_up(incl, 4); if (p >= 4) incl += u4;
    int gExcl = incl - sC;
    int totC = __shfl(incl, lane | 7);  // group's last lane = total in-deg
    int tR = sR;  // group-reduce out-degree
    tR += __shfl_xor(tR, 1);
    tR += __shfl_xor(tR, 2);
    tR += __shfl_xor(tR, 4);
    int run = gExcl;
#pragma unroll
    for (int j = 0; j < KPT; ++j) {
        unsigned v = (unsigned)packedHist[(base + j) * N + b];
        pre16[(base + j) * N + b] = (unsigned short)run;
        run += (int)(v >> 16);
    }
    if (p == 0) {
        dinv[b] = 1.0f / (float)(tR + 1);  // +1 self-loop
        cnt[b] = min(totC, PAD);
    }
}

// D3: (A) HsU = bf16x2(H*dinv) pre-scale (grid-stride, fully contiguous);
//     (B) padded-CSR fill of u16 src, hist-partition-aligned, stateless.
__global__ __launch_bounds__(256) void fillscale_kernel(
    const int* __restrict__ ei, int E, int Epb, int N,
    const unsigned short* __restrict__ pre16,
    const unsigned short* __restrict__ rank16,
    unsigned short* __restrict__ edge_src,
    const float* __restrict__ H, const float* __restrict__ dinv,
    unsigned* __restrict__ HsU, int subPerBlk) {
    // phase A: pre-scale + bf16 pack
    {
        int tid = blockIdx.x * 256 + threadIdx.x;
        int total = N * (DFEAT / 2);
        int stride = gridDim.x * 256;
        const float2* __restrict__ H2 = (const float2*)H;
        for (int i = tid; i < total; i += stride) {
            float d = dinv[i >> 6];
            float2 hh = H2[i];
            HsU[i] = bf16rne(hh.x * d) | (bf16rne(hh.y * d) << 16);
        }
    }
    // phase B: fill (block-uniform hist-partition id)
    int b = blockIdx.x / subPerBlk;
    int sub = blockIdx.x - b * subPerBlk;
    if (b < NBLK) {
        int e0 = b * Epb, e1 = min(E, e0 + Epb);
        const unsigned short* __restrict__ pre = pre16 + b * N;
        int stride = subPerBlk * 256;
        for (int e = e0 + sub * 256 + threadIdx.x; e < e1; e += stride) {
            int c = ei[E + e];
            int slot = (int)pre[c] + (int)rank16[e];
            if (slot < PAD)  // statistically impossible; keeps memory safe
                edge_src[c * PAD + slot] = (unsigned short)ei[e];
        }
    }
}

// D4: fused aggregate + matmul + bias + ReLU + LayerNorm. One node per wave
// (10000 waves). Gather = pure adds of prescaled bf16 rows, fp32 acc. Row
// staged in per-wave-private LDS (wave-local ds ordering via lgkmcnt +
// sched_barrier). Matmul: 32 dwordx4 WbT4 loads + 32 ds_read_b128 broadcast.
__global__ __launch_bounds__(256) void aggmmln_kernel(
    const unsigned* __restrict__ HsU, const uint4* __restrict__ WbT4,
    const int* __restrict__ cnt, const unsigned short* __restrict__ edge_src,
    const float* __restrict__ bias, const float* __restrict__ gamma,
    const float* __restrict__ beta, float* __restrict__ out, int N) {
    __shared__ float rows[4][DFEAT];  // 2 KB, one row per wave
    int t = threadIdx.x;
    int w = t >> 6, l = t & 63;
    int c = blockIdx.x * 4 + w;

    // ---- gather this wave's node row (fp32 acc, prescaled bf16 msgs) ----
    float x = 0.f, y = 0.f;
    if (c < N) {
        unsigned su = HsU[c * 64 + l];  // self message (prescaled)
        x = bflo(su);
        y = bfhi(su);
        int deg = cnt[c];
        const unsigned short* __restrict__ es = edge_src + c * PAD;  // 256B-aligned
        int e = 0;
        for (; e + 8 <= deg; e += 8) {
            uint4 iv = *(const uint4*)(es + e);  // 8 u16 indices
            int s0 = iv.x & 0xffff, s1 = iv.x >> 16;
            int s2 = iv.y & 0xffff, s3 = iv.y >> 16;
            int s4 = iv.z & 0xffff, s5 = iv.z >> 16;
            int s6 = iv.w & 0xffff, s7 = iv.w >> 16;
            unsigned u0 = HsU[s0 * 64 + l], u1 = HsU[s1 * 64 + l];
            unsigned u2 = HsU[s2 * 64 + l], u3 = HsU[s3 * 64 + l];
            unsigned u4 = HsU[s4 * 64 + l], u5 = HsU[s5 * 64 + l];
            unsigned u6 = HsU[s6 * 64 + l], u7 = HsU[s7 * 64 + l];
            x += bflo(u0) + bflo(u1) + bflo(u2) + bflo(u3) +
                 bflo(u4) + bflo(u5) + bflo(u6) + bflo(u7);
            y += bfhi(u0) + bfhi(u1) + bfhi(u2) + bfhi(u3) +
                 bfhi(u4) + bfhi(u5) + bfhi(u6) + bfhi(u7);
        }
        for (; e < deg; ++e) {
            unsigned u = HsU[(int)es[e] * 64 + l];
            x += bflo(u);
            y += bfhi(u);
        }
    }
    *(float2*)&rows[w][2 * l] = make_float2(x, y);
    asm volatile("s_waitcnt lgkmcnt(0)" ::: "memory");
    __builtin_amdgcn_sched_barrier(0);

    // ---- matmul (this wave's node) + bias + ReLU + LN ----
    float a0 = bias[l], a1 = bias[l + 64];
#pragma unroll 8
    for (int kk = 0; kk < 32; ++kk) {
        uint4 wv = WbT4[kk * 64 + l];                 // (A0,B0,A1,B1)
        float4 xv = *(const float4*)&rows[w][4 * kk]; // broadcast b128 read
        a0 += xv.x * bflo(wv.x) + xv.y * bfhi(wv.x) +
              xv.z * bflo(wv.z) + xv.w * bfhi(wv.z);
        a1 += xv.x * bflo(wv.y) + xv.y * bfhi(wv.y) +
              xv.z * bflo(wv.w) + xv.w * bfhi(wv.w);
    }
    float v0 = fmaxf(a0, 0.f), v1 = fmaxf(a1, 0.f);
    float s = v0 + v1, q = v0 * v0 + v1 * v1;
    for (int o = 32; o; o >>= 1) {
        s += __shfl_xor(s, o);
        q += __shfl_xor(q, o);
    }
    float mean = s * (1.0f / 128.0f);
    float var = q * (1.0f / 128.0f) - mean * mean;
    float rstd = rsqrtf(var + 1e-5f);
    if (c < N) {
        out[(size_t)c * 128 + l] = (v0 - mean) * rstd * gamma[l] + beta[l];
        out[(size_t)c * 128 + l + 64] =
            (v1 - mean) * rstd * gamma[l + 64] + beta[l + 64];
    }
}

extern "C" void kernel_launch(void* const* d_in, const int* in_sizes, int n_in,
                              void* d_out, int out_size, void* d_ws, size_t ws_size,
                              hipStream_t stream) {
    const float* H = (const float*)d_in[0];
    const int* ei = (const int*)d_in[1];
    const float* W = (const float*)d_in[3];
    const float* bias = (const float*)d_in[4];
    const float* gamma = (const float*)d_in[5];
    const float* beta = (const float*)d_in[6];
    float* out = (float*)d_out;

    const int N = in_sizes[0] / DFEAT;  // 10000 (<= MAXN)
    const int E = in_sizes[1] / 2;      // 640000
    const int Epb = (E + NBLK - 1) / NBLK;  // 5000 (< 65536 for u16 ranks)

    char* wp = (char*)d_ws;
    auto alloc = [&](size_t bytes) {
        char* p = wp;
        wp += (bytes + 255) & ~(size_t)255;
        return p;
    };
    int* packedHist = (int*)alloc((size_t)NBLK * N * 4);             // 5.12 MB
    unsigned short* pre16 = (unsigned short*)alloc((size_t)NBLK * N * 2);  // 2.56 MB
    unsigned short* rank16 = (unsigned short*)alloc((size_t)E * 2);  // 1.28 MB
    unsigned short* edge_src = (unsigned short*)alloc((size_t)N * PAD * 2);  // 2.56 MB
    unsigned* HsU = (unsigned*)alloc((size_t)N * (DFEAT / 2) * 4);   // 2.56 MB
    uint4* WbT4 = (uint4*)alloc((size_t)32 * 64 * 16);               // 32 KB
    int* cnt = (int*)alloc((size_t)N * 4);
    float* dinv = (float*)alloc((size_t)N * 4);
    (void)ws_size;

    hist_pack_kernel<<<NBLK, 1024, 0, stream>>>(ei, E, Epb, N, W,
                                                packedHist, rank16, WbT4);
    colscan_kernel<<<(N * SPLIT + 255) / 256, 256, 0, stream>>>(
        packedHist, pre16, dinv, cnt, N);
    {
        int subPerBlk = 8;  // grid = 1024 blocks
        fillscale_kernel<<<NBLK * subPerBlk, 256, 0, stream>>>(
            ei, E, Epb, N, pre16, rank16, edge_src, H, dinv, HsU, subPerBlk);
    }
    aggmmln_kernel<<<(N + 3) / 4, 256, 0, stream>>>(
        HsU, WbT4, cnt, edge_src, bias, gamma, beta, out, N);
}

// Round 14
// 60.453 us; speedup vs baseline: 1.0051x; 1.0051x over previous
//
#include <hip/hip_runtime.h>

// GNN layer: deg-normalized aggregation -> Linear+ReLU -> LayerNorm
// N=10000, E=640000, D=128. 4 dispatches (R12 structure + fused prescale):
//  D1 hist_pack: 128-block LDS packed histogram + per-edge ranks;
//                side-work: WbT = bf16x2(W) transposed.
//  D2 colscan:   8 lanes/bin shfl-combined block-prefix scan -> u16 pre16,
//                in-deg cnt (capped PAD); FUSED prescale: group holds the
//                out-degree sum in-register -> dinv -> packs HsU[b][:]
//                = bf16x2(H[b][:] * dinv) (no dinv global array).
//  D3 fill:      pure padded-CSR fill of u16 src indices (stateless).
//  D4 aggmmln:   one node per wave (10000 waves): gather-add prescaled bf16
//                rows (fp32 acc, 8-edge unroll), stage row in per-wave LDS,
//                matmul vs global WbT (L1-resident) + bias + ReLU + LN.
// Isolated A/B vs R11: readlane matmul (the bundled change) stays reverted;
// only the prescale fusion is retried on top of the best (R12) kernel.

#define DFEAT 128
#define MAXN 10240
#define NBLK 128     // histogram partitions
#define PAD 128      // CSR slots/node (mean in-deg 64, max ~101; guarded)
#define SPLIT 8
#define KPT (NBLK / SPLIT)  // 16 hist-blocks per colscan lane

__device__ __forceinline__ unsigned bf16rne(float f) {
    unsigned u = __float_as_uint(f);
    return (u + 0x7fffu + ((u >> 16) & 1u)) >> 16;
}
__device__ __forceinline__ float bflo(unsigned u) { return __uint_as_float(u << 16); }
__device__ __forceinline__ float bfhi(unsigned u) { return __uint_as_float(u & 0xffff0000u); }

// D1: packed per-block histogram (low16=source/out-deg, high16=dest/in-deg;
// Epb=5000 so halves never carry), per-edge dest ranks; WbT pack side-work.
__global__ __launch_bounds__(1024) void hist_pack_kernel(
    const int* __restrict__ ei, int E, int Epb, int N,
    const float* __restrict__ W, int* __restrict__ packedHist,
    unsigned short* __restrict__ rank16, unsigned* __restrict__ WbT) {
    __shared__ unsigned h[MAXN];
    int t = threadIdx.x, b = blockIdx.x;
    for (int i = t; i < N; i += 1024) h[i] = 0u;
    __syncthreads();
    {
        int e0 = b * Epb, e1 = min(E, e0 + Epb);
        for (int e = e0 + t; e < e1; e += 1024) {
            atomicAdd(&h[ei[e]], 1u);                               // source
            unsigned old = atomicAdd(&h[ei[E + e]], 0x10000u);      // dest
            rank16[e] = (unsigned short)(old >> 16);
        }
    }
    __syncthreads();
    for (int i = t; i < N; i += 1024) packedHist[b * N + i] = (int)h[i];
    // side-work: WbT[k2*128+d] = bf16x2(W[d][2k2], W[d][2k2+1])
    {
        int gid = b * 1024 + t;
        if (gid < 128 * (DFEAT / 2)) {
            int k2 = gid >> 7, d = gid & 127;
            WbT[gid] = bf16rne(W[d * 128 + 2 * k2]) |
                       (bf16rne(W[d * 128 + 2 * k2 + 1]) << 16);
        }
    }
}

// D2: per-bin, 8 lanes each scan 16 hist-blocks; shfl-combine across the
// 8-lane group; exclusive prefixes -> u16 pre16; in-deg cnt (capped);
// fused HsU prescale using in-register dinv.
__global__ __launch_bounds__(256) void colscan_kernel(
    const int* __restrict__ packedHist, unsigned short* __restrict__ pre16,
    const float* __restrict__ H, unsigned* __restrict__ HsU,
    int* __restrict__ cnt, int N) {
    int tid = blockIdx.x * 256 + threadIdx.x;
    int b = tid >> 3, p = tid & 7;
    if (b >= N) return;  // whole 8-lane groups drop together
    int lane = threadIdx.x & 63;
    int base = p * KPT;
    int sR = 0, sC = 0;
#pragma unroll
    for (int j = 0; j < KPT; ++j) {
        unsigned v = (unsigned)packedHist[(base + j) * N + b];
        sR += (int)(v & 0xffffu);
        sC += (int)(v >> 16);
    }
    int incl = sC;
    int u1 = __shfl_up(incl, 1); if (p >= 1) incl += u1;
    int u2 = __shfl_up(incl, 2); if (p >= 2) incl += u2;
    int u4 = __shfl_up(incl, 4); if (p >= 4) incl += u4;
    int gExcl = incl - sC;
    int totC = __shfl(incl, lane | 7);  // group's last lane = total in-deg
    int tR = sR;  // group-reduce out-degree (butterfly stays in 8-lane group)
    tR += __shfl_xor(tR, 1);
    tR += __shfl_xor(tR, 2);
    tR += __shfl_xor(tR, 4);
    int run = gExcl;
#pragma unroll
    for (int j = 0; j < KPT; ++j) {
        unsigned v = (unsigned)packedHist[(base + j) * N + b];
        pre16[(base + j) * N + b] = (unsigned short)run;
        run += (int)(v >> 16);
    }
    // fused prescale: HsU[b*64 + j*8 + p] = bf16x2(H * dinv)
    {
        float d = 1.0f / (float)(tR + 1);  // +1 self-loop
        const float2* __restrict__ H2 = (const float2*)H;
#pragma unroll
        for (int j = 0; j < 8; ++j) {
            int idx = b * 64 + j * 8 + p;
            float2 hh = H2[idx];
            HsU[idx] = bf16rne(hh.x * d) | (bf16rne(hh.y * d) << 16);
        }
    }
    if (p == 0) cnt[b] = min(totC, PAD);
}

// D3: pure padded-CSR fill of u16 src, hist-partition-aligned, stateless.
__global__ __launch_bounds__(256) void fill_kernel(
    const int* __restrict__ ei, int E, int Epb, int N,
    const unsigned short* __restrict__ pre16,
    const unsigned short* __restrict__ rank16,
    unsigned short* __restrict__ edge_src, int subPerBlk) {
    int b = blockIdx.x / subPerBlk;
    int sub = blockIdx.x - b * subPerBlk;
    if (b >= NBLK) return;
    int e0 = b * Epb, e1 = min(E, e0 + Epb);
    const unsigned short* __restrict__ pre = pre16 + b * N;
    int stride = subPerBlk * 256;
    for (int e = e0 + sub * 256 + threadIdx.x; e < e1; e += stride) {
        int c = ei[E + e];
        int slot = (int)pre[c] + (int)rank16[e];
        if (slot < PAD)  // statistically impossible; keeps memory safe
            edge_src[c * PAD + slot] = (unsigned short)ei[e];
    }
}

// D4: fused aggregate + matmul + bias + ReLU + LayerNorm. One node per wave
// (10000 waves). Gather = pure adds of prescaled bf16 rows, fp32 acc. Row
// staged in per-wave-private LDS (wave-local ds ordering via lgkmcnt +
// sched_barrier). W from global WbT (32KB, L1-resident).
__global__ __launch_bounds__(256) void aggmmln_kernel(
    const unsigned* __restrict__ HsU, const unsigned* __restrict__ WbT,
    const int* __restrict__ cnt, const unsigned short* __restrict__ edge_src,
    const float* __restrict__ bias, const float* __restrict__ gamma,
    const float* __restrict__ beta, float* __restrict__ out, int N) {
    __shared__ float rows[4][DFEAT];  // 2 KB, one row per wave
    int t = threadIdx.x;
    int w = t >> 6, l = t & 63;
    int c = blockIdx.x * 4 + w;

    // ---- gather this wave's node row (fp32 acc, prescaled bf16 msgs) ----
    float x = 0.f, y = 0.f;
    if (c < N) {
        unsigned su = HsU[c * 64 + l];  // self message (prescaled)
        x = bflo(su);
        y = bfhi(su);
        int deg = cnt[c];
        const unsigned short* __restrict__ es = edge_src + c * PAD;  // 256B-aligned
        int e = 0;
        for (; e + 8 <= deg; e += 8) {
            uint4 iv = *(const uint4*)(es + e);  // 8 u16 indices
            int s0 = iv.x & 0xffff, s1 = iv.x >> 16;
            int s2 = iv.y & 0xffff, s3 = iv.y >> 16;
            int s4 = iv.z & 0xffff, s5 = iv.z >> 16;
            int s6 = iv.w & 0xffff, s7 = iv.w >> 16;
            unsigned u0 = HsU[s0 * 64 + l], u1 = HsU[s1 * 64 + l];
            unsigned u2 = HsU[s2 * 64 + l], u3 = HsU[s3 * 64 + l];
            unsigned u4 = HsU[s4 * 64 + l], u5 = HsU[s5 * 64 + l];
            unsigned u6 = HsU[s6 * 64 + l], u7 = HsU[s7 * 64 + l];
            x += bflo(u0) + bflo(u1) + bflo(u2) + bflo(u3) +
                 bflo(u4) + bflo(u5) + bflo(u6) + bflo(u7);
            y += bfhi(u0) + bfhi(u1) + bfhi(u2) + bfhi(u3) +
                 bfhi(u4) + bfhi(u5) + bfhi(u6) + bfhi(u7);
        }
        for (; e < deg; ++e) {
            unsigned u = HsU[(int)es[e] * 64 + l];
            x += bflo(u);
            y += bfhi(u);
        }
    }
    *(float2*)&rows[w][2 * l] = make_float2(x, y);
    asm volatile("s_waitcnt lgkmcnt(0)" ::: "memory");
    __builtin_amdgcn_sched_barrier(0);

    // ---- matmul (this wave's node) + bias + ReLU + LN ----
    float a0 = bias[l], a1 = bias[l + 64];
#pragma unroll 8
    for (int k2 = 0; k2 < 64; ++k2) {
        unsigned wA = WbT[k2 * 128 + l];        // W[l][2k2..]
        unsigned wB = WbT[k2 * 128 + l + 64];   // W[l+64][2k2..]
        float2 xv = *(const float2*)&rows[w][2 * k2];  // broadcast read
        a0 += xv.x * bflo(wA) + xv.y * bfhi(wA);
        a1 += xv.x * bflo(wB) + xv.y * bfhi(wB);
    }
    float v0 = fmaxf(a0, 0.f), v1 = fmaxf(a1, 0.f);
    float s = v0 + v1, q = v0 * v0 + v1 * v1;
    for (int o = 32; o; o >>= 1) {
        s += __shfl_xor(s, o);
        q += __shfl_xor(q, o);
    }
    float mean = s * (1.0f / 128.0f);
    float var = q * (1.0f / 128.0f) - mean * mean;
    float rstd = rsqrtf(var + 1e-5f);
    if (c < N) {
        out[(size_t)c * 128 + l] = (v0 - mean) * rstd * gamma[l] + beta[l];
        out[(size_t)c * 128 + l + 64] =
            (v1 - mean) * rstd * gamma[l + 64] + beta[l + 64];
    }
}

extern "C" void kernel_launch(void* const* d_in, const int* in_sizes, int n_in,
                              void* d_out, int out_size, void* d_ws, size_t ws_size,
                              hipStream_t stream) {
    const float* H = (const float*)d_in[0];
    const int* ei = (const int*)d_in[1];
    const float* W = (const float*)d_in[3];
    const float* bias = (const float*)d_in[4];
    const float* gamma = (const float*)d_in[5];
    const float* beta = (const float*)d_in[6];
    float* out = (float*)d_out;

    const int N = in_sizes[0] / DFEAT;  // 10000 (<= MAXN)
    const int E = in_sizes[1] / 2;      // 640000
    const int Epb = (E + NBLK - 1) / NBLK;  // 5000 (< 65536 for u16 ranks)

    char* wp = (char*)d_ws;
    auto alloc = [&](size_t bytes) {
        char* p = wp;
        wp += (bytes + 255) & ~(size_t)255;
        return p;
    };
    int* packedHist = (int*)alloc((size_t)NBLK * N * 4);             // 5.12 MB
    unsigned short* pre16 = (unsigned short*)alloc((size_t)NBLK * N * 2);  // 2.56 MB
    unsigned short* rank16 = (unsigned short*)alloc((size_t)E * 2);  // 1.28 MB
    unsigned short* edge_src = (unsigned short*)alloc((size_t)N * PAD * 2);  // 2.56 MB
    unsigned* HsU = (unsigned*)alloc((size_t)N * (DFEAT / 2) * 4);   // 2.56 MB
    unsigned* WbT = (unsigned*)alloc((size_t)128 * (DFEAT / 2) * 4); // 32 KB
    int* cnt = (int*)alloc((size_t)N * 4);
    (void)ws_size;

    hist_pack_kernel<<<NBLK, 1024, 0, stream>>>(ei, E, Epb, N, W,
                                                packedHist, rank16, WbT);
    colscan_kernel<<<(N * SPLIT + 255) / 256, 256, 0, stream>>>(
        packedHist, pre16, H, HsU, cnt, N);
    {
        int subPerBlk = 8;  // grid = 1024 blocks
        fill_kernel<<<NBLK * subPerBlk, 256, 0, stream>>>(
            ei, E, Epb, N, pre16, rank16, edge_src, subPerBlk);
    }
    aggmmln_kernel<<<(N + 3) / 4, 256, 0, stream>>>(
        HsU, WbT, cnt, edge_src, bias, gamma, beta, out, N);
}

// Round 15
// 59.168 us; speedup vs baseline: 1.0269x; 1.0217x over previous
//
#include <hip/hip_runtime.h>

// GNN layer: deg-normalized aggregation -> Linear+ReLU -> LayerNorm
// N=10000, E=640000, D=128. 4 dispatches (R12 structure, best measured:
// 59.3us). Final configuration.
//  D1 hist_pack:  128-block LDS packed histogram + per-edge ranks;
//                 side-work: WbT = bf16x2(W) transposed.
//  D2 colscan:    8 lanes/bin shfl-combined block-prefix scan -> u16 pre16
//                 (packedHist stays read-only), in-deg cnt (capped PAD),
//                 dinv = 1/(outdeg+1).
//  D3 fillscale:  (A) HsU = bf16x2(H * dinv) pre-scale (contiguous pass);
//                 (B) padded-CSR fill of u16 src indices (stateless).
//  D4 aggmmln:    one node per wave (10000 waves): gather-add prescaled bf16
//                 rows (fp32 acc, 8-edge unroll), stage row in per-wave LDS,
//                 matmul vs global WbT (L1-resident) + bias + ReLU + LN.
// Falsified alternatives: global atomics (R1: 62us count kernel), mega-kernel
// grid barriers (R5/R6: ~30us/barrier agent-scope cache maintenance on
// 8 XCDs), 4-nodes/wave D4 (R8: occupancy starvation), readlane matmul
// (R11), prescale-fusion into colscan (R14: neutral), WbT4 quads (R13:
// neutral). Remaining time is the serial-dispatch + latency floor.

#define DFEAT 128
#define MAXN 10240
#define NBLK 128     // histogram partitions
#define PAD 160      // CSR slots/node (mean in-deg 64, max ~110; guarded)
#define SPLIT 8
#define KPT (NBLK / SPLIT)  // 16 hist-blocks per colscan lane

__device__ __forceinline__ unsigned bf16rne(float f) {
    unsigned u = __float_as_uint(f);
    return (u + 0x7fffu + ((u >> 16) & 1u)) >> 16;
}
__device__ __forceinline__ float bflo(unsigned u) { return __uint_as_float(u << 16); }
__device__ __forceinline__ float bfhi(unsigned u) { return __uint_as_float(u & 0xffff0000u); }

// D1: packed per-block histogram (low16=source/out-deg, high16=dest/in-deg;
// Epb=5000 so halves never carry), per-edge dest ranks; WbT pack side-work.
__global__ __launch_bounds__(1024) void hist_pack_kernel(
    const int* __restrict__ ei, int E, int Epb, int N,
    const float* __restrict__ W, int* __restrict__ packedHist,
    unsigned short* __restrict__ rank16, unsigned* __restrict__ WbT) {
    __shared__ unsigned h[MAXN];
    int t = threadIdx.x, b = blockIdx.x;
    for (int i = t; i < N; i += 1024) h[i] = 0u;
    __syncthreads();
    {
        int e0 = b * Epb, e1 = min(E, e0 + Epb);
        for (int e = e0 + t; e < e1; e += 1024) {
            atomicAdd(&h[ei[e]], 1u);                               // source
            unsigned old = atomicAdd(&h[ei[E + e]], 0x10000u);      // dest
            rank16[e] = (unsigned short)(old >> 16);
        }
    }
    __syncthreads();
    for (int i = t; i < N; i += 1024) packedHist[b * N + i] = (int)h[i];
    // side-work: WbT[k2*128+d] = bf16x2(W[d][2k2], W[d][2k2+1])
    {
        int gid = b * 1024 + t;
        if (gid < 128 * (DFEAT / 2)) {
            int k2 = gid >> 7, d = gid & 127;
            WbT[gid] = bf16rne(W[d * 128 + 2 * k2]) |
                       (bf16rne(W[d * 128 + 2 * k2 + 1]) << 16);
        }
    }
}

// D2: per-bin, 8 lanes each scan 16 hist-blocks; shfl-combine across the
// 8-lane group; write exclusive prefixes to u16 pre16 (prefix <= in-deg
// ~110 << 65535); in-deg cnt (capped PAD); dinv.
__global__ __launch_bounds__(256) void colscan_kernel(
    const int* __restrict__ packedHist, unsigned short* __restrict__ pre16,
    float* __restrict__ dinv, int* __restrict__ cnt, int N) {
    int tid = blockIdx.x * 256 + threadIdx.x;
    int b = tid >> 3, p = tid & 7;
    if (b >= N) return;  // whole 8-lane groups drop together
    int lane = threadIdx.x & 63;
    int base = p * KPT;
    int sR = 0, sC = 0;
#pragma unroll
    for (int j = 0; j < KPT; ++j) {
        unsigned v = (unsigned)packedHist[(base + j) * N + b];
        sR += (int)(v & 0xffffu);
        sC += (int)(v >> 16);
    }
    int incl = sC;
    int u1 = __shfl_up(incl, 1); if (p >= 1) incl += u1;
    int u2 = __shfl_up(incl, 2); if (p >= 2) incl += u2;
    int u4 = __shfl_up(incl, 4); if (p >= 4) incl += u4;
    int gExcl = incl - sC;
    int totC = __shfl(incl, lane | 7);  // group's last lane = total in-deg
    int tR = sR;  // group-reduce out-degree
    tR += __shfl_xor(tR, 1);
    tR += __shfl_xor(tR, 2);
    tR += __shfl_xor(tR, 4);
    int run = gExcl;
#pragma unroll
    for (int j = 0; j < KPT; ++j) {
        unsigned v = (unsigned)packedHist[(base + j) * N + b];
        pre16[(base + j) * N + b] = (unsigned short)run;
        run += (int)(v >> 16);
    }
    if (p == 0) {
        dinv[b] = 1.0f / (float)(tR + 1);  // +1 self-loop
        cnt[b] = min(totC, PAD);
    }
}

// D3: (A) HsU = bf16x2(H*dinv) pre-scale (grid-stride, fully contiguous);
//     (B) padded-CSR fill of u16 src, hist-partition-aligned, stateless.
__global__ __launch_bounds__(256) void fillscale_kernel(
    const int* __restrict__ ei, int E, int Epb, int N,
    const unsigned short* __restrict__ pre16,
    const unsigned short* __restrict__ rank16,
    unsigned short* __restrict__ edge_src,
    const float* __restrict__ H, const float* __restrict__ dinv,
    unsigned* __restrict__ HsU, int subPerBlk) {
    // phase A: pre-scale + bf16 pack
    {
        int tid = blockIdx.x * 256 + threadIdx.x;
        int total = N * (DFEAT / 2);
        int stride = gridDim.x * 256;
        const float2* __restrict__ H2 = (const float2*)H;
        for (int i = tid; i < total; i += stride) {
            float d = dinv[i >> 6];
            float2 hh = H2[i];
            HsU[i] = bf16rne(hh.x * d) | (bf16rne(hh.y * d) << 16);
        }
    }
    // phase B: fill (block-uniform hist-partition id)
    int b = blockIdx.x / subPerBlk;
    int sub = blockIdx.x - b * subPerBlk;
    if (b < NBLK) {
        int e0 = b * Epb, e1 = min(E, e0 + Epb);
        const unsigned short* __restrict__ pre = pre16 + b * N;
        int stride = subPerBlk * 256;
        for (int e = e0 + sub * 256 + threadIdx.x; e < e1; e += stride) {
            int c = ei[E + e];
            int slot = (int)pre[c] + (int)rank16[e];
            if (slot < PAD)  // statistically impossible; keeps memory safe
                edge_src[c * PAD + slot] = (unsigned short)ei[e];
        }
    }
}

// D4: fused aggregate + matmul + bias + ReLU + LayerNorm. One node per wave
// (10000 waves). Gather = pure adds of prescaled bf16 rows, fp32 acc. Row
// staged in per-wave-private LDS (wave-local ds ordering via lgkmcnt +
// sched_barrier, guide rule 18). W from global WbT (32KB, L1-resident).
__global__ __launch_bounds__(256) void aggmmln_kernel(
    const unsigned* __restrict__ HsU, const unsigned* __restrict__ WbT,
    const int* __restrict__ cnt, const unsigned short* __restrict__ edge_src,
    const float* __restrict__ bias, const float* __restrict__ gamma,
    const float* __restrict__ beta, float* __restrict__ out, int N) {
    __shared__ float rows[4][DFEAT];  // 2 KB, one row per wave
    int t = threadIdx.x;
    int w = t >> 6, l = t & 63;
    int c = blockIdx.x * 4 + w;

    // ---- gather this wave's node row (fp32 acc, prescaled bf16 msgs) ----
    float x = 0.f, y = 0.f;
    if (c < N) {
        unsigned su = HsU[c * 64 + l];  // self message (prescaled)
        x = bflo(su);
        y = bfhi(su);
        int deg = cnt[c];
        const unsigned short* __restrict__ es = edge_src + c * PAD;  // 320B-aligned
        int e = 0;
        for (; e + 8 <= deg; e += 8) {
            uint4 iv = *(const uint4*)(es + e);  // 8 u16 indices
            int s0 = iv.x & 0xffff, s1 = iv.x >> 16;
            int s2 = iv.y & 0xffff, s3 = iv.y >> 16;
            int s4 = iv.z & 0xffff, s5 = iv.z >> 16;
            int s6 = iv.w & 0xffff, s7 = iv.w >> 16;
            unsigned u0 = HsU[s0 * 64 + l], u1 = HsU[s1 * 64 + l];
            unsigned u2 = HsU[s2 * 64 + l], u3 = HsU[s3 * 64 + l];
            unsigned u4 = HsU[s4 * 64 + l], u5 = HsU[s5 * 64 + l];
            unsigned u6 = HsU[s6 * 64 + l], u7 = HsU[s7 * 64 + l];
            x += bflo(u0) + bflo(u1) + bflo(u2) + bflo(u3) +
                 bflo(u4) + bflo(u5) + bflo(u6) + bflo(u7);
            y += bfhi(u0) + bfhi(u1) + bfhi(u2) + bfhi(u3) +
                 bfhi(u4) + bfhi(u5) + bfhi(u6) + bfhi(u7);
        }
        for (; e < deg; ++e) {
            unsigned u = HsU[(int)es[e] * 64 + l];
            x += bflo(u);
            y += bfhi(u);
        }
    }
    *(float2*)&rows[w][2 * l] = make_float2(x, y);
    asm volatile("s_waitcnt lgkmcnt(0)" ::: "memory");
    __builtin_amdgcn_sched_barrier(0);

    // ---- matmul (this wave's node) + bias + ReLU + LN ----
    float a0 = bias[l], a1 = bias[l + 64];
#pragma unroll 8
    for (int k2 = 0; k2 < 64; ++k2) {
        unsigned wA = WbT[k2 * 128 + l];        // W[l][2k2..]
        unsigned wB = WbT[k2 * 128 + l + 64];   // W[l+64][2k2..]
        float2 xv = *(const float2*)&rows[w][2 * k2];  // broadcast read
        a0 += xv.x * bflo(wA) + xv.y * bfhi(wA);
        a1 += xv.x * bflo(wB) + xv.y * bfhi(wB);
    }
    float v0 = fmaxf(a0, 0.f), v1 = fmaxf(a1, 0.f);
    float s = v0 + v1, q = v0 * v0 + v1 * v1;
    for (int o = 32; o; o >>= 1) {
        s += __shfl_xor(s, o);
        q += __shfl_xor(q, o);
    }
    float mean = s * (1.0f / 128.0f);
    float var = q * (1.0f / 128.0f) - mean * mean;
    float rstd = rsqrtf(var + 1e-5f);
    if (c < N) {
        out[(size_t)c * 128 + l] = (v0 - mean) * rstd * gamma[l] + beta[l];
        out[(size_t)c * 128 + l + 64] =
            (v1 - mean) * rstd * gamma[l + 64] + beta[l + 64];
    }
}

extern "C" void kernel_launch(void* const* d_in, const int* in_sizes, int n_in,
                              void* d_out, int out_size, void* d_ws, size_t ws_size,
                              hipStream_t stream) {
    const float* H = (const float*)d_in[0];
    const int* ei = (const int*)d_in[1];
    const float* W = (const float*)d_in[3];
    const float* bias = (const float*)d_in[4];
    const float* gamma = (const float*)d_in[5];
    const float* beta = (const float*)d_in[6];
    float* out = (float*)d_out;

    const int N = in_sizes[0] / DFEAT;  // 10000 (<= MAXN)
    const int E = in_sizes[1] / 2;      // 640000
    const int Epb = (E + NBLK - 1) / NBLK;  // 5000 (< 65536 for u16 ranks)

    char* wp = (char*)d_ws;
    auto alloc = [&](size_t bytes) {
        char* p = wp;
        wp += (bytes + 255) & ~(size_t)255;
        return p;
    };
    int* packedHist = (int*)alloc((size_t)NBLK * N * 4);             // 5.12 MB
    unsigned short* pre16 = (unsigned short*)alloc((size_t)NBLK * N * 2);  // 2.56 MB
    unsigned short* rank16 = (unsigned short*)alloc((size_t)E * 2);  // 1.28 MB
    unsigned short* edge_src = (unsigned short*)alloc((size_t)N * PAD * 2);  // 3.2 MB
    unsigned* HsU = (unsigned*)alloc((size_t)N * (DFEAT / 2) * 4);   // 2.56 MB
    unsigned* WbT = (unsigned*)alloc((size_t)128 * (DFEAT / 2) * 4); // 32 KB
    int* cnt = (int*)alloc((size_t)N * 4);
    float* dinv = (float*)alloc((size_t)N * 4);
    (void)ws_size;

    hist_pack_kernel<<<NBLK, 1024, 0, stream>>>(ei, E, Epb, N, W,
                                                packedHist, rank16, WbT);
    colscan_kernel<<<(N * SPLIT + 255) / 256, 256, 0, stream>>>(
        packedHist, pre16, dinv, cnt, N);
    {
        int subPerBlk = 8;  // grid = 1024 blocks
        fillscale_kernel<<<NBLK * subPerBlk, 256, 0, stream>>>(
            ei, E, Epb, N, pre16, rank16, edge_src, H, dinv, HsU, subPerBlk);
    }
    aggmmln_kernel<<<(N + 3) / 4, 256, 0, stream>>>(
        HsU, WbT, cnt, edge_src, bias, gamma, beta, out, N);
}